// Round 4
// baseline (124.875 us; speedup 1.0000x reference)
//
#include <hip/hip_runtime.h>
#include <hip/hip_bf16.h>

#define HWP 9216   // H*W
#define HH  96
#define WW  96
#define CC  256    // Cin == Cout
#define NB  2

typedef __attribute__((ext_vector_type(8))) short bf16x8;
typedef __attribute__((ext_vector_type(4))) float f32x4;

__device__ inline unsigned short f2bf(float f) {
  union { __hip_bfloat16 h; unsigned short u; } cvt;
  cvt.h = __float2bfloat16(f);
  return cvt.u;
}
__device__ inline float bf_lo(unsigned int u) { return __uint_as_float(u << 16); }
__device__ inline float bf_hi(unsigned int u) { return __uint_as_float(u & 0xffff0000u); }

// R13: k_prep folded away. k_main converts pw_w/off_w f32->bf16 inline
// (R12-verified identical numerics); k_gather stages dw_w transposed in LDS.
// PITFALL (R12): hipLaunchCooperativeKernel + this_grid().sync() under the
// harness graph capture does NOT provide a working grid barrier (absmax 5.28,
// stale halo xpb reads). Do NOT fuse across the xpb producer/consumer
// boundary — keep separate dispatches.
// NOTE: ~88us of dur_us is harness workspace-poison fills (2 x 44us); the
// controllable kernel budget is ~36us at R11.

// ---- fused: xp = pw_w . x  (bf16 MFMA, 32 pix x 256 ch per block, BK=32)
//            + offs = off_w . xp + off_b  (MFMA epilogue on the Cs tile)
// 2-phase dbuf (R11). 1-D grid, XCD-aligned: block g -> XCD class e=g%8
// produces pixel strip [e*1152,(e+1)*1152) per batch so k_gather (same
// decode) finds xp in the LOCAL per-XCD L2.
// Pitfalls kept: register-prefetch of MFMA frags (R6/R7) REGRESSED; BK=64
// (R9) REGRESSED. Keep BK=32, pad-40 layout (2-way = free).
__global__ __launch_bounds__(256) void k_main(const float* __restrict__ x,
                                              const float* __restrict__ pw_w,
                                              const float* __restrict__ off_w,
                                              const float* __restrict__ off_b,
                                              unsigned short* __restrict__ xpb,
                                              float* __restrict__ offs) {
  __shared__ unsigned short As[2][32 * 40];    // [pix][k] dbuf
  __shared__ unsigned short Bs[2][256 * 40];   // [n][k] dbuf; Bs[0] reused as Cs

  // XCD-aligned decode: g -> (e, b, m); strip block x = e*36 + m
  int g   = blockIdx.x;          // 0..575
  int e   = g & 7;
  int idx = g >> 3;              // 0..71
  int b   = idx / 36;
  int m   = idx - b * 36;        // 0..35
  int pix0 = (e * 36 + m) * 32;  // local pixel within batch

  int t    = threadIdx.x;
  int lane = t & 63;
  int w    = t >> 6;
  int mw = (w & 1) * 16;     // wave pixel tile
  int nw = (w >> 1) * 128;   // wave channel half
  int r = lane & 15, q = lane >> 4;

  f32x4 acc[8] = {};

  const float* xg = x + (size_t)b * CC * HWP + pix0;
  int sc = t >> 3;           // channel within 32-chunk
  int sp = (t & 7) * 4;      // pixel offset
  int nB = t >> 2;           // B row within 64-group
  int c8 = (t & 3) * 8;      // B k-offset

  // ---- prologue: stage K-step 0 into buf 0 (B converted inline from f32)
  {
    f32x4 xv = __builtin_nontemporal_load((const f32x4*)(xg + (size_t)sc * HWP + sp));
    As[0][(sp + 0) * 40 + sc] = f2bf(xv.x);
    As[0][(sp + 1) * 40 + sc] = f2bf(xv.y);
    As[0][(sp + 2) * 40 + sc] = f2bf(xv.z);
    As[0][(sp + 3) * 40 + sc] = f2bf(xv.w);
#pragma unroll
    for (int rep = 0; rep < 4; ++rep) {
      int n = rep * 64 + nB;
      const float* wp = pw_w + n * 256 + c8;
      float4 w0 = *(const float4*)wp;
      float4 w1 = *(const float4*)(wp + 4);
      union { ushort4 h[2]; uint4 q4; } pk;
      pk.h[0] = make_ushort4(f2bf(w0.x), f2bf(w0.y), f2bf(w0.z), f2bf(w0.w));
      pk.h[1] = make_ushort4(f2bf(w1.x), f2bf(w1.y), f2bf(w1.z), f2bf(w1.w));
      *(uint4*)&Bs[0][n * 40 + c8] = pk.q4;
    }
  }
  __syncthreads();

  // ---- main loop: 1 barrier per K-step, prefetch t+1 overlapped with MFMA(t)
  for (int kt = 0; kt < 8; ++kt) {
    int cur = kt & 1;
    f32x4 xv;
    float4 b0[4], b1[4];
    bool pre = (kt < 7);
    if (pre) {
      int k0 = (kt + 1) * 32;
      xv = __builtin_nontemporal_load((const f32x4*)(xg + (size_t)(k0 + sc) * HWP + sp));
#pragma unroll
      for (int rep = 0; rep < 4; ++rep) {
        const float* wp = pw_w + (rep * 64 + nB) * 256 + k0 + c8;
        b0[rep] = *(const float4*)wp;
        b1[rep] = *(const float4*)(wp + 4);
      }
    }
    bf16x8 a = *(const bf16x8*)&As[cur][(mw + r) * 40 + q * 8];
#pragma unroll
    for (int nt = 0; nt < 8; ++nt) {
      bf16x8 bb = *(const bf16x8*)&Bs[cur][(nw + nt * 16 + r) * 40 + q * 8];
      acc[nt] = __builtin_amdgcn_mfma_f32_16x16x32_bf16(a, bb, acc[nt], 0, 0, 0);
    }
    if (pre) {
      int nx = cur ^ 1;
      As[nx][(sp + 0) * 40 + sc] = f2bf(xv.x);
      As[nx][(sp + 1) * 40 + sc] = f2bf(xv.y);
      As[nx][(sp + 2) * 40 + sc] = f2bf(xv.z);
      As[nx][(sp + 3) * 40 + sc] = f2bf(xv.w);
#pragma unroll
      for (int rep = 0; rep < 4; ++rep) {
        int n = rep * 64 + nB;
        union { ushort4 h[2]; uint4 q4; } pk;
        pk.h[0] = make_ushort4(f2bf(b0[rep].x), f2bf(b0[rep].y), f2bf(b0[rep].z), f2bf(b0[rep].w));
        pk.h[1] = make_ushort4(f2bf(b1[rep].x), f2bf(b1[rep].y), f2bf(b1[rep].z), f2bf(b1[rep].w));
        *(uint4*)&Bs[nx][n * 40 + c8] = pk.q4;
      }
    }
    __syncthreads();
  }

  // Cs aliases Bs[0]: last K-step read buf 1; final sync drained buf 0 reads.
  unsigned short* Cs = &Bs[0][0];   // [pix][ch] bf16, pad 264 (8448 <= 10240 shorts)

  // C/D: col = lane&15 (ch), row = q*4+rr (pix) -> Cs[pix][ch] bf16
#pragma unroll
  for (int nt = 0; nt < 8; ++nt)
#pragma unroll
    for (int rr = 0; rr < 4; ++rr)
      Cs[(mw + q * 4 + rr) * 264 + nw + nt * 16 + r] = f2bf(acc[nt][rr]);
  __syncthreads();

  // write xpb coalesced: 64 B contiguous per thread
  {
    int pix = t >> 3, c32 = (t & 7) * 32;
    unsigned short* o = xpb + ((size_t)b * HWP + pix0 + pix) * CC + c32;
#pragma unroll
    for (int j = 0; j < 4; ++j)
      *(uint4*)(o + j * 8) = *(const uint4*)&Cs[pix * 264 + c32 + j * 8];
  }

  // offset epilogue: offs[pix, o] = sum_c Cs[pix][c] * off_w[o][c] + off_b[o]
  // off_w rows >= 18: bb = 0 (equivalent to old zero-padded wb).
  {
    int mw2 = (w & 1) * 16;    // pixel tile
    int nw2 = (w >> 1) * 16;   // o tile (0 or 16)
    int row = nw2 + r;
    f32x4 oacc = {};
#pragma unroll
    for (int ks = 0; ks < CC; ks += 32) {
      bf16x8 a = *(const bf16x8*)&Cs[(mw2 + r) * 264 + ks + q * 8];
      bf16x8 bb = {};
      if (row < 18) {
        const float* wp = off_w + row * 256 + ks + q * 8;
        float4 w0 = *(const float4*)wp;
        float4 w1 = *(const float4*)(wp + 4);
        union { unsigned short u[8]; bf16x8 v; } pk;
        pk.u[0] = f2bf(w0.x); pk.u[1] = f2bf(w0.y); pk.u[2] = f2bf(w0.z); pk.u[3] = f2bf(w0.w);
        pk.u[4] = f2bf(w1.x); pk.u[5] = f2bf(w1.y); pk.u[6] = f2bf(w1.z); pk.u[7] = f2bf(w1.w);
        bb = pk.v;
      }
      oacc = __builtin_amdgcn_mfma_f32_16x16x32_bf16(a, bb, oacc, 0, 0, 0);
    }
    if (row < 18) {
      float ob = off_b[row];
      size_t base = ((size_t)b * HWP + pix0 + mw2 + q * 4) * 20 + row;
#pragma unroll
      for (int rr = 0; rr < 4; ++rr)
        offs[base + (size_t)rr * 20] = oacc[rr] + ob;
    }
  }
}

// ---- gather + depthwise: 16 pixels/block, XCD-ALIGNED to k_main's strips.
// R10: wave-uniform per-(pixel,tap) decode precomputed by 144 threads into
// LDS; main loop reads via broadcast ds_read_b128 and does only per-channel
// work. R13: dw_w staged transposed into LDS (dvs[tap][ch]) at block start.
// Hard-won pitfalls:
//  * NO launch-bounds min-wave arg (R6: forced VGPR 64 -> scratch spills, 3x)
//  * NO nontemporal output stores (R4: 4x WRITE_SIZE amplification)
//  * NO 8-ch/lane half-wave scheme (R8: VGPR 176, occupancy 9%, +25% time)
__global__ __launch_bounds__(256) void k_gather(const unsigned short* __restrict__ xp,
                                                const float* __restrict__ offs,
                                                const float* __restrict__ dw_w,
                                                float* __restrict__ out) {
  __shared__ float Cs[16][257];
  __shared__ float4 Wt[16][9];   // bilinear weights per (pixel, tap)
  __shared__ int4   Ad[16][9];   // corner row byte-offsets per (pixel, tap)
  __shared__ float  dvs[9][257]; // dw_w transposed [tap][ch]

  // XCD-aligned decode: g -> (e, b, m2); chunk c = e*72 + m2 (16 px each)
  int g   = blockIdx.x;          // 0..1151
  int e   = g & 7;
  int idx = g >> 3;              // 0..143
  int b   = idx / 72;
  int m2  = idx - b * 72;        // 0..71
  int c   = e * 72 + m2;         // 0..575
  int pix0 = b * HWP + c * 16;   // global pixel

  int wave = threadIdx.x >> 6;
  int lane = threadIdx.x & 63;
  int c0 = lane * 4;

  int hw0 = pix0 - b * HWP;
  const unsigned short* xb = xp + (size_t)b * HWP * CC;
  const float* opb = offs + (size_t)pix0 * 20;

  // ---- phase 0a: stage dw_w transposed (9 scalar loads/thread, 9 KB total)
  {
    int t = threadIdx.x;
#pragma unroll
    for (int kk = 0; kk < 9; ++kk)
      dvs[kk][t] = dw_w[t * 9 + kk];
  }

  // ---- phase 0b: 144 threads compute the wave-uniform per-(pixel,tap) data
  {
    int tp = threadIdx.x;
    if (tp < 144) {
      int ip = tp / 9;               // pixel 0..15
      int kk = tp - ip * 9;          // tap 0..8
      int hw = hw0 + ip;
      int h = hw / WW;
      int wq = hw - h * WW;
      float2 o2 = *(const float2*)(opb + ip * 20 + 2 * kk);
      float y = (float)(h + kk / 3 - 1) + o2.x;
      float x = (float)(wq + kk % 3 - 1) + o2.y;
      float y0f = floorf(y), x0f = floorf(x);
      float fy = y - y0f, fx = x - x0f;
      int y0 = (int)y0f, x0 = (int)x0f;
      int y1 = y0 + 1, x1 = x0 + 1;
      bool vy0 = (y0 >= 0) & (y0 < HH);
      bool vy1 = (y1 >= 0) & (y1 < HH);
      bool vx0 = (x0 >= 0) & (x0 < WW);
      bool vx1 = (x1 >= 0) & (x1 < WW);
      int y0c = y0 < 0 ? 0 : (y0 > HH - 1 ? HH - 1 : y0);
      int y1c = y1 < 0 ? 0 : (y1 > HH - 1 ? HH - 1 : y1);
      int x0c = x0 < 0 ? 0 : (x0 > WW - 1 ? WW - 1 : x0);
      int x1c = x1 < 0 ? 0 : (x1 > WW - 1 ? WW - 1 : x1);
      Wt[ip][kk] = make_float4(
          (1.f - fy) * (1.f - fx) * ((vy0 && vx0) ? 1.f : 0.f),
          (1.f - fy) * fx         * ((vy0 && vx1) ? 1.f : 0.f),
          fy * (1.f - fx)         * ((vy1 && vx0) ? 1.f : 0.f),
          fy * fx                 * ((vy1 && vx1) ? 1.f : 0.f));
      Ad[ip][kk] = make_int4((y0c * WW + x0c) * (CC * 2), (y0c * WW + x1c) * (CC * 2),
                             (y1c * WW + x0c) * (CC * 2), (y1c * WW + x1c) * (CC * 2));
    }
  }
  __syncthreads();

  // ---- main loop: per-channel work only (unpack + FMA); addresses/weights
  // come from LDS broadcast reads.
  const char* xbc = (const char*)xb;
  unsigned lb = (unsigned)(lane * 8);   // this lane's 4-channel byte offset

  float acc[4][4] = {};
#pragma unroll
  for (int kk = 0; kk < 9; ++kk) {
    float4 dv = *(const float4*)&dvs[kk][c0];
#pragma unroll
    for (int p4 = 0; p4 < 4; ++p4) {
      int ip = wave * 4 + p4;
      float4 wv = Wt[ip][kk];
      int4 av = Ad[ip][kk];
      uint2 u00 = *(const uint2*)(xbc + ((unsigned)av.x + lb));
      uint2 u01 = *(const uint2*)(xbc + ((unsigned)av.y + lb));
      uint2 u10 = *(const uint2*)(xbc + ((unsigned)av.z + lb));
      uint2 u11 = *(const uint2*)(xbc + ((unsigned)av.w + lb));

      float s0 = wv.x * bf_lo(u00.x) + wv.y * bf_lo(u01.x) + wv.z * bf_lo(u10.x) + wv.w * bf_lo(u11.x);
      float s1 = wv.x * bf_hi(u00.x) + wv.y * bf_hi(u01.x) + wv.z * bf_hi(u10.x) + wv.w * bf_hi(u11.x);
      float s2 = wv.x * bf_lo(u00.y) + wv.y * bf_lo(u01.y) + wv.z * bf_lo(u10.y) + wv.w * bf_lo(u11.y);
      float s3 = wv.x * bf_hi(u00.y) + wv.y * bf_hi(u01.y) + wv.z * bf_hi(u10.y) + wv.w * bf_hi(u11.y);

      acc[p4][0] += dv.x * s0;
      acc[p4][1] += dv.y * s1;
      acc[p4][2] += dv.z * s2;
      acc[p4][3] += dv.w * s3;
    }
  }
#pragma unroll
  for (int p4 = 0; p4 < 4; ++p4)
    *(float4*)&Cs[wave * 4 + p4][c0] =
        make_float4(acc[p4][0], acc[p4][1], acc[p4][2], acc[p4][3]);
  __syncthreads();
  // write-out: thread t = channel, 16 consecutive pixels = 64 B contiguous per thread.
  int ch = threadIdx.x;
  float* ob = out + (size_t)b * CC * HWP + (size_t)ch * HWP + hw0;
#pragma unroll
  for (int p4 = 0; p4 < 4; ++p4) {
    float4 v = make_float4(Cs[p4 * 4 + 0][ch], Cs[p4 * 4 + 1][ch],
                           Cs[p4 * 4 + 2][ch], Cs[p4 * 4 + 3][ch]);
    *(float4*)(ob + p4 * 4) = v;
  }
}

extern "C" void kernel_launch(void* const* d_in, const int* in_sizes, int n_in,
                              void* d_out, int out_size, void* d_ws, size_t ws_size,
                              hipStream_t stream) {
  (void)in_sizes; (void)n_in; (void)out_size; (void)ws_size;
  const float* x     = (const float*)d_in[0];
  const float* pw_w  = (const float*)d_in[1];
  const float* off_w = (const float*)d_in[2];
  const float* off_b = (const float*)d_in[3];
  const float* dw_w  = (const float*)d_in[4];
  float* out = (float*)d_out;

  char* ws = (char*)d_ws;
  unsigned short* xpb = (unsigned short*)ws;            // B*HW*C bf16 = 9,437,184 B
  float* offs = (float*)(ws + 9437184);                 // B*HW*20 f32 = 1,474,560 B

  k_main  <<<576, 256, 0, stream>>>(x, pw_w, off_w, off_b, xpb, offs);
  k_gather<<<1152, 256, 0, stream>>>(xpb, offs, dw_w, out);
}